// Round 17
// baseline (728.843 us; speedup 1.0000x reference)
//
#include <hip/hip_runtime.h>
#include <hip/hip_cooperative_groups.h>

namespace cg = cooperative_groups;

#define N_NODES 10000
#define N_EDGES 320000
#define DIN 512
#define DHID 512
#define DOUT 256

typedef __bf16 bf16x8 __attribute__((ext_vector_type(8)));
typedef float f32x4 __attribute__((ext_vector_type(4)));
typedef unsigned short ushort_t;
typedef unsigned int uint_t;

__device__ __forceinline__ float b2f(ushort_t u){
    union { uint_t i; float f; } v; v.i = (uint_t)u << 16; return v.f;
}
__device__ __forceinline__ float blo(uint_t v){
    union { uint_t i; float f; } u; u.i = v << 16; return u.f;
}
__device__ __forceinline__ float bhi(uint_t v){
    union { uint_t i; float f; } u; u.i = v & 0xffff0000u; return u.f;
}
__device__ __forceinline__ ushort_t f2b(float f){
    union { float f; uint_t i; } v; v.f = f;
    uint_t i = v.i;
    return (ushort_t)((i + 0x7fffu + ((i >> 16) & 1u)) >> 16); // RNE
}

__device__ __forceinline__ void gll16(const ushort_t* g, ushort_t* l){
    __builtin_amdgcn_global_load_lds(
        (const __attribute__((address_space(1))) unsigned int*)g,
        (__attribute__((address_space(3))) unsigned int*)l,
        16, 0, 0);
}

// ---------------- fused front-end (cooperative): pe/cvt/zero -> degree -> scan -> scatter

struct CvtArgs { const float* s[8]; const float* s2[8]; ushort_t* d[8]; int n[8]; };

__global__ void k_front(const int* __restrict__ e_src, const int* __restrict__ e_dst,
                        const float* __restrict__ w_pe, const float* __restrict__ b_pe,
                        ushort_t* __restrict__ h0, CvtArgs a,
                        int* __restrict__ deg, uint_t* __restrict__ zp,
                        int* __restrict__ row_ptr, int* __restrict__ cursor,
                        int* __restrict__ srcs){
    cg::grid_group grid = cg::this_grid();
    __shared__ float lt[64][68];     // pe tile; aliased as int[256] for the scan
    int t = threadIdx.x;

    // ---- phase A: pe transpose + weight cvt + zeroing (2320 jobs, grid-stride) ----
    for (int job = blockIdx.x; job < 2320; job += gridDim.x){
        if (job < 1256){
            int n0 = (job % 157) * 64, i0 = (job / 157) * 64;
            int nc = (t & 15) * 4, ir = t >> 4;
            #pragma unroll
            for (int p = 0; p < 4; ++p){
                int i_loc = ir + p * 16;
                float4 v = {0.f, 0.f, 0.f, 0.f};
                if (n0 + nc < N_NODES)
                    v = *(const float4*)&w_pe[(size_t)(i0 + i_loc) * N_NODES + n0 + nc];
                lt[nc + 0][i_loc] = v.x;
                lt[nc + 1][i_loc] = v.y;
                lt[nc + 2][i_loc] = v.z;
                lt[nc + 3][i_loc] = v.w;
            }
            __syncthreads();
            int ic = t & 7, nr = t >> 3;
            #pragma unroll
            for (int p = 0; p < 2; ++p){
                int n_loc = nr + p * 32;
                int n = n0 + n_loc;
                if (n < N_NODES){
                    uint4 u;
                    u.x = (uint_t)f2b(lt[n_loc][ic*8+0] + b_pe[i0+ic*8+0])
                        | ((uint_t)f2b(lt[n_loc][ic*8+1] + b_pe[i0+ic*8+1]) << 16);
                    u.y = (uint_t)f2b(lt[n_loc][ic*8+2] + b_pe[i0+ic*8+2])
                        | ((uint_t)f2b(lt[n_loc][ic*8+3] + b_pe[i0+ic*8+3]) << 16);
                    u.z = (uint_t)f2b(lt[n_loc][ic*8+4] + b_pe[i0+ic*8+4])
                        | ((uint_t)f2b(lt[n_loc][ic*8+5] + b_pe[i0+ic*8+5]) << 16);
                    u.w = (uint_t)f2b(lt[n_loc][ic*8+6] + b_pe[i0+ic*8+6])
                        | ((uint_t)f2b(lt[n_loc][ic*8+7] + b_pe[i0+ic*8+7]) << 16);
                    *(uint4*)&h0[(size_t)n * DIN + i0 + ic * 8] = u;
                }
            }
        } else if (job < 2280){
            int j = job - 1256;
            int m = j >> 7;
            int i = (((j & 127) * 256) + t) * 8;
            if (i < a.n[m]){
                const float* sp = a.s[m] + i;
                float4 f0 = *(const float4*)sp;
                float4 f1 = *(const float4*)(sp + 4);
                if (a.s2[m]){
                    const float* sq = a.s2[m] + i;
                    float4 g0 = *(const float4*)sq;
                    float4 g1 = *(const float4*)(sq + 4);
                    f0.x += g0.x; f0.y += g0.y; f0.z += g0.z; f0.w += g0.w;
                    f1.x += g1.x; f1.y += g1.y; f1.z += g1.z; f1.w += g1.w;
                }
                uint4 u;
                u.x = (uint_t)f2b(f0.x) | ((uint_t)f2b(f0.y) << 16);
                u.y = (uint_t)f2b(f0.z) | ((uint_t)f2b(f0.w) << 16);
                u.z = (uint_t)f2b(f1.x) | ((uint_t)f2b(f1.y) << 16);
                u.w = (uint_t)f2b(f1.z) | ((uint_t)f2b(f1.w) << 16);
                *(uint4*)&a.d[m][i] = u;
            }
        } else {
            int i = (job - 2280) * 256 + t;
            if (i < N_NODES) deg[i] = 0;
            if (i < 256) zp[i] = 0u;
        }
        __syncthreads();   // protect lt before next job reuses it
    }
    __threadfence();
    grid.sync();

    // ---- phase B: degree histogram ----
    for (int job = blockIdx.x; job < 1250; job += gridDim.x){
        int e = job * 256 + t;
        if (e < N_EDGES) atomicAdd(&deg[e_dst[e]], 1);
    }
    __threadfence();
    grid.sync();

    // ---- phase C: prefix scan (block 0; 40 elems/thread serial + block scan) ----
    if (blockIdx.x == 0){
        int* part = (int*)&lt[0][0];
        int base = t * 40;
        int loc[40];
        int s = 0;
        #pragma unroll
        for (int i = 0; i < 40; ++i){
            int idx = base + i;
            int v = (idx < N_NODES) ? deg[idx] : 0;
            s += v; loc[i] = s;
        }
        part[t] = s;
        __syncthreads();
        int val = s;
        for (int off = 1; off < 256; off <<= 1){
            int x = (t >= off) ? part[t - off] : 0;
            __syncthreads();
            val += x; part[t] = val;
            __syncthreads();
        }
        int exc = val - s;
        if (t == 0) row_ptr[0] = 0;
        int run = exc;
        #pragma unroll
        for (int i = 0; i < 40; ++i){
            int idx = base + i;
            if (idx < N_NODES){
                row_ptr[idx + 1] = exc + loc[i];
                cursor[idx] = run;
            }
            run = exc + loc[i];
        }
    }
    __threadfence();
    grid.sync();

    // ---- phase D: bucket scatter ----
    for (int job = blockIdx.x; job < 1250; job += gridDim.x){
        int e = job * 256 + t;
        if (e < N_EDGES){
            int p = atomicAdd(&cursor[e_dst[e]], 1);
            srcs[p] = e_src[e];
        }
    }
}

// ---------------- mean aggregation v6: readlane, 64-edge superblock ------------
// grid (2500, 4): blockIdx.y = 128-dim panel (2.56MB < 4MB per-XCD L2).
// wave = one node; lane covers 2 dims (4B). ONE 256B index load per superblock,
// per-edge index extracted with v_readlane. Tail padded with `dummy` zero row.

#define AGG_EDGE(e, CH) { \
    int s_ = __builtin_amdgcn_readlane(sr, (e)); \
    uint_t v_ = *(const uint_t*)&X[((size_t)(uint_t)s_ << 9) + col]; \
    CH##0 += blo(v_); CH##1 += bhi(v_); }

__global__ __launch_bounds__(256) void k_agg(
    const ushort_t* __restrict__ X, const int* __restrict__ row_ptr,
    const int* __restrict__ srcs, ushort_t* __restrict__ out, int dummy)
{
    int w = threadIdx.x >> 6, lane = threadIdx.x & 63;
    int n = blockIdx.x * 4 + w;
    int col = blockIdx.y * 128 + lane * 2;
    int beg = row_ptr[n], end = row_ptr[n + 1];
    int deg = end - beg;
    float a0=0.f,a1=0.f, p0=0.f,p1=0.f, c0=0.f,c1=0.f, d0=0.f,d1=0.f;

    for (int base = beg; base < end; base += 64){
        int rem = end - base;
        int sr = (lane < rem) ? srcs[base + lane] : dummy;
        int cnt = rem < 64 ? rem : 64;
        #pragma unroll
        for (int k = 0; k < 4; ++k){
            if (k * 16 < cnt){
                int L = k * 16;
                AGG_EDGE(L + 0,  a) AGG_EDGE(L + 1,  p) AGG_EDGE(L + 2,  c) AGG_EDGE(L + 3,  d)
                AGG_EDGE(L + 4,  a) AGG_EDGE(L + 5,  p) AGG_EDGE(L + 6,  c) AGG_EDGE(L + 7,  d)
                AGG_EDGE(L + 8,  a) AGG_EDGE(L + 9,  p) AGG_EDGE(L + 10, c) AGG_EDGE(L + 11, d)
                AGG_EDGE(L + 12, a) AGG_EDGE(L + 13, p) AGG_EDGE(L + 14, c) AGG_EDGE(L + 15, d)
            }
        }
    }

    float r0 = (a0 + p0) + (c0 + d0);
    float r1 = (a1 + p1) + (c1 + d1);
    float inv = (deg > 0) ? 1.f / (float)deg : 1.f;
    uint_t o = (uint_t)f2b(r0 * inv) | ((uint_t)f2b(r1 * inv) << 16);
    *(uint_t*)&out[(size_t)n * 512 + col] = o;
}

// ---------------- final aggregation: fin = Q + mean_agg(P) ----------------

#define AGGF_EDGE(e, CH) { \
    int s_ = __builtin_amdgcn_readlane(sr, (e)); \
    uint_t v_ = *(const uint_t*)&P[((size_t)(uint_t)s_ << 8) + col]; \
    CH##0 += blo(v_); CH##1 += bhi(v_); }

__global__ __launch_bounds__(256) void k_aggf(
    const ushort_t* __restrict__ P, const int* __restrict__ row_ptr,
    const int* __restrict__ srcs, const float* __restrict__ Q,
    float* __restrict__ fin, float* __restrict__ mid2, int dummy)
{
    int w = threadIdx.x >> 6, lane = threadIdx.x & 63;
    int n = blockIdx.x * 4 + w;
    int col = blockIdx.y * 128 + lane * 2;
    int beg = row_ptr[n], end = row_ptr[n + 1];
    int deg = end - beg;
    float a0=0.f,a1=0.f, p0=0.f,p1=0.f, c0=0.f,c1=0.f, d0=0.f,d1=0.f;

    for (int base = beg; base < end; base += 64){
        int rem = end - base;
        int sr = (lane < rem) ? srcs[base + lane] : dummy;
        int cnt = rem < 64 ? rem : 64;
        #pragma unroll
        for (int k = 0; k < 4; ++k){
            if (k * 16 < cnt){
                int L = k * 16;
                AGGF_EDGE(L + 0,  a) AGGF_EDGE(L + 1,  p) AGGF_EDGE(L + 2,  c) AGGF_EDGE(L + 3,  d)
                AGGF_EDGE(L + 4,  a) AGGF_EDGE(L + 5,  p) AGGF_EDGE(L + 6,  c) AGGF_EDGE(L + 7,  d)
                AGGF_EDGE(L + 8,  a) AGGF_EDGE(L + 9,  p) AGGF_EDGE(L + 10, c) AGGF_EDGE(L + 11, d)
                AGGF_EDGE(L + 12, a) AGGF_EDGE(L + 13, p) AGGF_EDGE(L + 14, c) AGGF_EDGE(L + 15, d)
            }
        }
    }

    float r0 = (a0 + p0) + (c0 + d0);
    float r1 = (a1 + p1) + (c1 + d1);
    float inv = (deg > 0) ? 1.f / (float)deg : 1.f;
    float2 q = *(const float2*)&Q[(size_t)n * 256 + col];
    float2 o;
    o.x = q.x + r0 * inv;
    o.y = q.y + r1 * inv;
    *(float2*)&fin [(size_t)n * 256 + col] = o;
    *(float2*)&mid2[(size_t)n * 256 + col] = o;
}

// ---------------- fused SAGE layer (layers 0/1): one-batch BM=160, BN=64 --------
// T2 bank-swizzle (both-sides, measured neutral -> kept); 2-phase pipeline.
// Y(f32) = leaky(X@Ws^T + Agg@Wn^T + b) + X@Wr^T + rb ; bf16 shadow to YB

template<int DO, int BN, bool ACT, bool WRITE_BF>
__global__ __launch_bounds__(256, 2) void k_layer(
    const ushort_t* __restrict__ X, const ushort_t* __restrict__ G,
    const ushort_t* __restrict__ Ws, const ushort_t* __restrict__ Wn,
    const ushort_t* __restrict__ Wr,
    const float* __restrict__ b, const float* __restrict__ rb,
    float* __restrict__ Y, ushort_t* __restrict__ YB)
{
    constexpr int BM   = 160;
    constexpr int NT   = DO / BN;
    constexpr int WTN  = BN / 32;
    constexpr int NCH  = (2 * BM + 3 * BN) / 16;
    constexpr int CHPW = (NCH + 3) / 4;
    constexpr int OG   = BM * 32;
    constexpr int OS   = 2 * BM * 32;
    constexpr int WS32 = BN * 32;
    constexpr int BUFSZ = OS + 3 * WS32;
    __shared__ __align__(16) ushort_t smem[2][BUFSZ];

    int t = threadIdx.x;
    int bid = blockIdx.x;
    int r8 = bid & 7, q8 = bid >> 3;
    int m_t = (q8 / NT) * 8 + r8;
    int n_t = q8 % NT;
    if (m_t * BM >= N_NODES) return;
    int m0 = m_t * BM, n0 = n_t * BN;

    int lane = t & 63, w = t >> 6;
    int wr = w >> 1, wc = w & 1;

    const ushort_t* gptr[CHPW];
    int coff[CHPW];
    bool gv[CHPW];
    int rl = lane >> 2;
    int sl = ((lane & 3) ^ ((rl >> 1) & 3)) * 8;
    #pragma unroll
    for (int i = 0; i < CHPW; ++i){
        int qq = w * CHPW + i;
        gv[i] = (qq < NCH);
        int qc = gv[i] ? qq : 0;
        const ushort_t* gA; int rowbase, off;
        if (qc < 10)      { gA = X;  rowbase = m0 + qc * 16;        off = qc * 512; }
        else if (qc < 20) { gA = G;  rowbase = m0 + (qc - 10) * 16; off = OG + (qc - 10) * 512; }
        else {
            int q2 = qc - 20;
            int sec = q2 / (BN / 16), wi = q2 % (BN / 16);
            gA = (sec == 0) ? Ws : (sec == 1) ? Wn : Wr;
            rowbase = n0 + wi * 16;
            off = OS + sec * WS32 + wi * 512;
        }
        gptr[i] = gA + (size_t)(rowbase + rl) * 512 + sl;
        coff[i] = off;
    }

    f32x4 accS[5][WTN] = {}, accG[5][WTN] = {}, accR[5][WTN] = {};
    int r16 = lane & 15;
    int arow = wr * 80 + r16;
    int brow = wc * (BN / 2) + r16;
    int kk = ((lane >> 4) ^ ((r16 >> 1) & 3)) * 8;

    #pragma unroll
    for (int i = 0; i < CHPW; ++i) if (gv[i]) gll16(gptr[i], &smem[0][coff[i]]);
    __syncthreads();

    int cur = 0;
    for (int ks = 0; ks < 16; ++ks){
        if (ks < 15){
            int k0 = (ks + 1) * 32;
            #pragma unroll
            for (int i = 0; i < CHPW; ++i) if (gv[i]) gll16(gptr[i] + k0, &smem[cur ^ 1][coff[i]]);
        }

        const ushort_t* sb = smem[cur];
        bf16x8 ax[5], ag[5], bs[WTN], bn_[WTN], brr[WTN];
        #pragma unroll
        for (int m = 0; m < 5; ++m){
            ax[m] = *(const bf16x8*)&sb[(arow + m * 16) * 32 + kk];
            ag[m] = *(const bf16x8*)&sb[OG + (arow + m * 16) * 32 + kk];
        }
        #pragma unroll
        for (int n = 0; n < WTN; ++n){
            bs[n]  = *(const bf16x8*)&sb[OS            + (brow + n * 16) * 32 + kk];
            bn_[n] = *(const bf16x8*)&sb[OS + WS32     + (brow + n * 16) * 32 + kk];
            brr[n] = *(const bf16x8*)&sb[OS + 2 * WS32 + (brow + n * 16) * 32 + kk];
        }
        #pragma unroll
        for (int m = 0; m < 5; ++m)
            #pragma unroll
            for (int n = 0; n < WTN; ++n){
                accS[m][n] = __builtin_amdgcn_mfma_f32_16x16x32_bf16(ax[m], bs[n],  accS[m][n], 0, 0, 0);
                accG[m][n] = __builtin_amdgcn_mfma_f32_16x16x32_bf16(ag[m], bn_[n], accG[m][n], 0, 0, 0);
                accR[m][n] = __builtin_amdgcn_mfma_f32_16x16x32_bf16(ax[m], brr[n], accR[m][n], 0, 0, 0);
            }

        __syncthreads();
        cur ^= 1;
    }

    int col_l = lane & 15;
    int row_l = (lane >> 4) * 4;
    #pragma unroll
    for (int n = 0; n < WTN; ++n){
        int col = n0 + wc * (BN / 2) + n * 16 + col_l;
        float bb = b[col], rbb = rb[col];
        #pragma unroll
        for (int m = 0; m < 5; ++m){
            #pragma unroll
            for (int j = 0; j < 4; ++j){
                int row = m0 + wr * 80 + m * 16 + row_l + j;
                if (row < N_NODES){
                    float v = accS[m][n][j] + accG[m][n][j] + bb;
                    if (ACT) v = (v > 0.f) ? v : 0.01f * v;
                    v += accR[m][n][j] + rbb;
                    Y[(size_t)row * DO + col] = v;
                    if (WRITE_BF) YB[(size_t)row * DO + col] = f2b(v);
                }
            }
        }
    }
}

// ---------------- layer 2 GEMM: P = X@Wn2^T (bf16), Q = X@Wsr2^T + (b2+rb2) (f32) --

__global__ __launch_bounds__(256, 2) void k_layer2(
    const ushort_t* __restrict__ X,
    const ushort_t* __restrict__ Wn, const ushort_t* __restrict__ Wsr,
    const float* __restrict__ b, const float* __restrict__ rb,
    ushort_t* __restrict__ Pout, float* __restrict__ Qout)
{
    constexpr int BM = 160, BN = 32, NT = DOUT / BN;
    constexpr int NCH = 10 + 2 * (BN / 16);
    constexpr int CHPW = 4;
    constexpr int OWN = BM * 32;
    constexpr int OWS = OWN + BN * 32;
    constexpr int BUFSZ = OWS + BN * 32;
    __shared__ __align__(16) ushort_t smem[2][BUFSZ];

    int t = threadIdx.x;
    int bid = blockIdx.x;
    int r8 = bid & 7, q8 = bid >> 3;
    int m_t = (q8 / NT) * 8 + r8;
    int n_t = q8 % NT;
    if (m_t * BM >= N_NODES) return;
    int m0 = m_t * BM, n0 = n_t * BN;

    int lane = t & 63, w = t >> 6;
    int wr = w >> 1, wc = w & 1;

    const ushort_t* gptr[CHPW];
    int coff[CHPW];
    bool gv[CHPW];
    int rl = lane >> 2;
    int sl = ((lane & 3) ^ ((rl >> 1) & 3)) * 8;
    #pragma unroll
    for (int i = 0; i < CHPW; ++i){
        int qq = w * CHPW + i;
        gv[i] = (qq < NCH);
        int qc = gv[i] ? qq : 0;
        const ushort_t* gA; int rowbase, off;
        if (qc < 10)      { gA = X;   rowbase = m0 + qc * 16;        off = qc * 512; }
        else if (qc < 12) { gA = Wn;  rowbase = n0 + (qc - 10) * 16; off = OWN + (qc - 10) * 512; }
        else              { gA = Wsr; rowbase = n0 + (qc - 12) * 16; off = OWS + (qc - 12) * 512; }
        gptr[i] = gA + (size_t)(rowbase + rl) * 512 + sl;
        coff[i] = off;
    }

    f32x4 accP[5] = {}, accQ[5] = {};
    int r16 = lane & 15;
    int arow = wr * 80 + r16;
    int brow = wc * 16 + r16;
    int kk = ((lane >> 4) ^ ((r16 >> 1) & 3)) * 8;

    #pragma unroll
    for (int i = 0; i < CHPW; ++i) if (gv[i]) gll16(gptr[i], &smem[0][coff[i]]);
    __syncthreads();

    int cur = 0;
    for (int ks = 0; ks < 16; ++ks){
        if (ks < 15){
            int k0 = (ks + 1) * 32;
            #pragma unroll
            for (int i = 0; i < CHPW; ++i) if (gv[i]) gll16(gptr[i] + k0, &smem[cur ^ 1][coff[i]]);
        }

        const ushort_t* sb = smem[cur];
        bf16x8 ax[5];
        #pragma unroll
        for (int m = 0; m < 5; ++m)
            ax[m] = *(const bf16x8*)&sb[(arow + m * 16) * 32 + kk];
        bf16x8 bn_ = *(const bf16x8*)&sb[OWN + brow * 32 + kk];
        bf16x8 bsr = *(const bf16x8*)&sb[OWS + brow * 32 + kk];
        #pragma unroll
        for (int m = 0; m < 5; ++m){
            accP[m] = __builtin_amdgcn_mfma_f32_16x16x32_bf16(ax[m], bn_, accP[m], 0, 0, 0);
            accQ[m] = __builtin_amdgcn_mfma_f32_16x16x32_bf16(ax[m], bsr, accQ[m], 0, 0, 0);
        }

        __syncthreads();
        cur ^= 1;
    }

    int col_l = lane & 15;
    int row_l = (lane >> 4) * 4;
    int col = n0 + wc * 16 + col_l;
    float bb = b[col] + rb[col];
    #pragma unroll
    for (int m = 0; m < 5; ++m){
        #pragma unroll
        for (int j = 0; j < 4; ++j){
            int row = m0 + wr * 80 + m * 16 + row_l + j;
            if (row < N_NODES){
                Qout[(size_t)row * DOUT + col] = accQ[m][j] + bb;
                Pout[(size_t)row * DOUT + col] = f2b(accP[m][j]);
            }
        }
    }
}

// ---------------- launch ----------------

extern "C" void kernel_launch(void* const* d_in, const int* in_sizes, int n_in,
                              void* d_out, int out_size, void* d_ws, size_t ws_size,
                              hipStream_t stream) {
    const int* edge  = (const int*)d_in[0];
    const int* e_src = edge;
    const int* e_dst = edge + N_EDGES;
    const float* w_pe = (const float*)d_in[1];
    const float* b_pe = (const float*)d_in[2];
    const float* ws0 = (const float*)d_in[3];
    const float* wn0 = (const float*)d_in[4];
    const float* b0  = (const float*)d_in[5];
    const float* wr0 = (const float*)d_in[6];
    const float* rb0 = (const float*)d_in[7];
    const float* ws1 = (const float*)d_in[8];
    const float* wn1 = (const float*)d_in[9];
    const float* b1  = (const float*)d_in[10];
    const float* wr1 = (const float*)d_in[11];
    const float* rb1 = (const float*)d_in[12];
    const float* ws2 = (const float*)d_in[13];
    const float* wn2 = (const float*)d_in[14];
    const float* b2  = (const float*)d_in[15];
    const float* wr2 = (const float*)d_in[16];
    const float* rb2 = (const float*)d_in[17];

    char* wsb = (char*)d_ws;
    ushort_t* h0   = (ushort_t*)wsb;                       // 10,240,000 B @ 0
    ushort_t* hb   = (ushort_t*)(wsb + 10240000);          // 10,240,000 B
    ushort_t* aggb = (ushort_t*)(wsb + 20480000);          // 10,240,000 B (pb aliases)
    ushort_t* wbf  = (ushort_t*)(wsb + 30720000);          // 3,932,160 B
    int* deg     = (int*)(wsb + 34652160);                 // 10016 ints
    int* row_ptr = deg + 10016;
    int* cursor  = row_ptr + 10016;
    int* srcs    = cursor + 10016;                         // 320000 ints -> ends 36,052,352
    uint_t* zp   = (uint_t*)(wsb + 36052992);              // 1KB zero row (1024-aligned)
    const int dummy_h0 = 35208;   // (36052992 - 0) / 1024          (1KB rows)
    const int dummy_hb = 25208;   // (36052992 - 10240000) / 1024   (1KB rows)
    const int dummy_pb = 30416;   // (36052992 - 20480000) / 512    (512B rows)

    ushort_t* wbf0s = wbf;
    ushort_t* wbf0n = wbf + 262144;
    ushort_t* wbf0r = wbf + 524288;
    ushort_t* wbf1s = wbf + 786432;
    ushort_t* wbf1n = wbf + 1048576;
    ushort_t* wbf1r = wbf + 1310720;
    ushort_t* wbf2n = wbf + 1572864;   // Wn2
    ushort_t* wbf2sr= wbf + 1703936;   // Ws2 + Wr2

    float* out  = (float*)d_out;
    float* fin  = out;               // [10000][256]
    float* mid0 = out + 2560000;     // [10000][512]
    float* mid1 = out + 7680000;     // [10000][512]
    float* mid2 = out + 12800000;    // [10000][256]
    ushort_t* pb = aggb;             // P = X@Wn2^T, bf16 [10000][256]

    CvtArgs ca;
    ca.s[0]=ws0; ca.s[1]=wn0; ca.s[2]=wr0;
    ca.s[3]=ws1; ca.s[4]=wn1; ca.s[5]=wr1;
    ca.s[6]=wn2; ca.s[7]=ws2;
    for (int i = 0; i < 8; ++i) ca.s2[i] = nullptr;
    ca.s2[7] = wr2;                                  // Wsr2 = Ws2 + Wr2
    ca.d[0]=wbf0s; ca.d[1]=wbf0n; ca.d[2]=wbf0r;
    ca.d[3]=wbf1s; ca.d[4]=wbf1n; ca.d[5]=wbf1r;
    ca.d[6]=wbf2n; ca.d[7]=wbf2sr;
    for (int i = 0; i < 6; ++i) ca.n[i] = 262144;
    ca.n[6] = 131072; ca.n[7] = 131072;

    // fused cooperative front-end: pe/cvt/zero -> degree -> scan -> scatter
    {
        void* args[] = {
            (void*)&e_src, (void*)&e_dst, (void*)&w_pe, (void*)&b_pe,
            (void*)&h0, (void*)&ca, (void*)&deg, (void*)&zp,
            (void*)&row_ptr, (void*)&cursor, (void*)&srcs
        };
        hipLaunchCooperativeKernel((const void*)k_front, dim3(1024), dim3(256),
                                   args, 0, stream);
    }

    k_agg<<<dim3(2500, 4), 256, 0, stream>>>(h0, row_ptr, srcs, aggb, dummy_h0);
    k_layer<512, 64, true, true ><<<dim3(512), 256, 0, stream>>>(
        h0, aggb, wbf0s, wbf0n, wbf0r, b0, rb0, mid0, hb);

    k_agg<<<dim3(2500, 4), 256, 0, stream>>>(hb, row_ptr, srcs, aggb, dummy_hb);
    k_layer<512, 64, true, true ><<<dim3(512), 256, 0, stream>>>(
        hb, aggb, wbf1s, wbf1n, wbf1r, b1, rb1, mid1, h0);

    // layer 2 via agg-commute: P = X@Wn2^T, Q = X@(Ws2+Wr2)^T + (b2+rb2);
    // fin = mid2 = Q + mean_agg(P)
    k_layer2<<<dim3(512), 256, 0, stream>>>(h0, wbf2n, wbf2sr, b2, rb2, pb, mid2);
    k_aggf<<<dim3(2500, 2), 256, 0, stream>>>(pb, row_ptr, srcs, mid2, fin, mid2, dummy_pb);
}

// Round 18
// 206.185 us; speedup vs baseline: 3.5349x; 3.5349x over previous
//
#include <hip/hip_runtime.h>

#define N_NODES 10000
#define N_EDGES 320000
#define DIN 512
#define DHID 512
#define DOUT 256

typedef __bf16 bf16x8 __attribute__((ext_vector_type(8)));
typedef float f32x4 __attribute__((ext_vector_type(4)));
typedef unsigned short ushort_t;
typedef unsigned int uint_t;

__device__ __forceinline__ float b2f(ushort_t u){
    union { uint_t i; float f; } v; v.i = (uint_t)u << 16; return v.f;
}
__device__ __forceinline__ float blo(uint_t v){
    union { uint_t i; float f; } u; u.i = v << 16; return u.f;
}
__device__ __forceinline__ float bhi(uint_t v){
    union { uint_t i; float f; } u; u.i = v & 0xffff0000u; return u.f;
}
__device__ __forceinline__ ushort_t f2b(float f){
    union { float f; uint_t i; } v; v.f = f;
    uint_t i = v.i;
    return (ushort_t)((i + 0x7fffu + ((i >> 16) & 1u)) >> 16); // RNE
}

__device__ __forceinline__ void gll16(const ushort_t* g, ushort_t* l){
    __builtin_amdgcn_global_load_lds(
        (const __attribute__((address_space(1))) unsigned int*)g,
        (__attribute__((address_space(3))) unsigned int*)l,
        16, 0, 0);
}

// ---------------- CSR build (degree/scan/scatter) ----------------

__global__ void k_degree(const int* __restrict__ dst, int* __restrict__ deg){
    int e = blockIdx.x * 256 + threadIdx.x;
    if (e < N_EDGES) atomicAdd(&deg[dst[e]], 1);
}

// 256 threads, 40 elems/thread serial scan in regs + 8-round block scan.
__global__ void k_scan(const int* __restrict__ deg, int* __restrict__ row_ptr,
                       int* __restrict__ cursor){
    __shared__ int part[256];
    int t = threadIdx.x;
    int base = t * 40;
    int loc[40];
    int s = 0;
    #pragma unroll
    for (int i = 0; i < 40; ++i){
        int idx = base + i;
        int v = (idx < N_NODES) ? deg[idx] : 0;
        s += v; loc[i] = s;          // thread-local inclusive
    }
    part[t] = s;
    __syncthreads();
    int val = s;
    for (int off = 1; off < 256; off <<= 1){
        int x = (t >= off) ? part[t - off] : 0;
        __syncthreads();
        val += x; part[t] = val;
        __syncthreads();
    }
    int exc = val - s;               // exclusive prefix of this thread's chunk
    if (t == 0) row_ptr[0] = 0;
    int run = exc;
    #pragma unroll
    for (int i = 0; i < 40; ++i){
        int idx = base + i;
        if (idx < N_NODES){
            row_ptr[idx + 1] = exc + loc[i];
            cursor[idx] = run;       // bucket start (exclusive)
        }
        run = exc + loc[i];
    }
}

__global__ void k_scatter(const int* __restrict__ src, const int* __restrict__ dst,
                          int* __restrict__ cursor, int* __restrict__ srcs){
    int e = blockIdx.x * 256 + threadIdx.x;
    if (e < N_EDGES){
        int p = atomicAdd(&cursor[dst[e]], 1);
        srcs[p] = src[e];
    }
}

// ---------------- fused prologue: pe transpose + weight cvt + zeroing ----------
// bid [0,1256): pe tile; [1256,2280): cvt chunk; [2280,2320): zero deg + zp.

struct CvtArgs { const float* s[8]; const float* s2[8]; ushort_t* d[8]; int n[8]; };

__global__ void k_pro(const float* __restrict__ w_pe, const float* __restrict__ b_pe,
                      ushort_t* __restrict__ h0, CvtArgs a,
                      int* __restrict__ deg, uint_t* __restrict__ zp){
    __shared__ float lt[64][68];
    int bid = blockIdx.x;
    int t = threadIdx.x;
    if (bid < 1256){
        // ---- pe = w_pe^T + b_pe, 64x64 tile, f32 -> bf16 ----
        int n0 = (bid % 157) * 64, i0 = (bid / 157) * 64;
        int nc = (t & 15) * 4, ir = t >> 4;
        #pragma unroll
        for (int p = 0; p < 4; ++p){
            int i_loc = ir + p * 16;
            float4 v = {0.f, 0.f, 0.f, 0.f};
            if (n0 + nc < N_NODES)
                v = *(const float4*)&w_pe[(size_t)(i0 + i_loc) * N_NODES + n0 + nc];
            lt[nc + 0][i_loc] = v.x;
            lt[nc + 1][i_loc] = v.y;
            lt[nc + 2][i_loc] = v.z;
            lt[nc + 3][i_loc] = v.w;
        }
        __syncthreads();
        int ic = t & 7, nr = t >> 3;
        #pragma unroll
        for (int p = 0; p < 2; ++p){
            int n_loc = nr + p * 32;
            int n = n0 + n_loc;
            if (n < N_NODES){
                uint4 u;
                u.x = (uint_t)f2b(lt[n_loc][ic*8+0] + b_pe[i0+ic*8+0])
                    | ((uint_t)f2b(lt[n_loc][ic*8+1] + b_pe[i0+ic*8+1]) << 16);
                u.y = (uint_t)f2b(lt[n_loc][ic*8+2] + b_pe[i0+ic*8+2])
                    | ((uint_t)f2b(lt[n_loc][ic*8+3] + b_pe[i0+ic*8+3]) << 16);
                u.z = (uint_t)f2b(lt[n_loc][ic*8+4] + b_pe[i0+ic*8+4])
                    | ((uint_t)f2b(lt[n_loc][ic*8+5] + b_pe[i0+ic*8+5]) << 16);
                u.w = (uint_t)f2b(lt[n_loc][ic*8+6] + b_pe[i0+ic*8+6])
                    | ((uint_t)f2b(lt[n_loc][ic*8+7] + b_pe[i0+ic*8+7]) << 16);
                *(uint4*)&h0[(size_t)n * DIN + i0 + ic * 8] = u;
            }
        }
    } else if (bid < 2280){
        // ---- weight f32 -> bf16 (job 7: d = f2b(s + s2)) ----
        int j = bid - 1256;
        int m = j >> 7;
        int i = (((j & 127) * 256) + t) * 8;
        if (i < a.n[m]){
            const float* sp = a.s[m] + i;
            float4 f0 = *(const float4*)sp;
            float4 f1 = *(const float4*)(sp + 4);
            if (a.s2[m]){
                const float* sq = a.s2[m] + i;
                float4 g0 = *(const float4*)sq;
                float4 g1 = *(const float4*)(sq + 4);
                f0.x += g0.x; f0.y += g0.y; f0.z += g0.z; f0.w += g0.w;
                f1.x += g1.x; f1.y += g1.y; f1.z += g1.z; f1.w += g1.w;
            }
            uint4 u;
            u.x = (uint_t)f2b(f0.x) | ((uint_t)f2b(f0.y) << 16);
            u.y = (uint_t)f2b(f0.z) | ((uint_t)f2b(f0.w) << 16);
            u.z = (uint_t)f2b(f1.x) | ((uint_t)f2b(f1.y) << 16);
            u.w = (uint_t)f2b(f1.z) | ((uint_t)f2b(f1.w) << 16);
            *(uint4*)&a.d[m][i] = u;
        }
    } else {
        int i = (bid - 2280) * 256 + t;
        if (i < N_NODES) deg[i] = 0;
        if (i < 256) zp[i] = 0u;
    }
}

// ---------------- mean aggregation v6: readlane, 64-edge superblock ------------
// grid (2500, 4): blockIdx.y = 128-dim panel (2.56MB < 4MB per-XCD L2).
// wave = one node; lane covers 2 dims (4B). ONE 256B index load per superblock,
// per-edge index extracted with v_readlane. Tail padded with `dummy` zero row.

#define AGG_EDGE(e, CH) { \
    int s_ = __builtin_amdgcn_readlane(sr, (e)); \
    uint_t v_ = *(const uint_t*)&X[((size_t)(uint_t)s_ << 9) + col]; \
    CH##0 += blo(v_); CH##1 += bhi(v_); }

__global__ __launch_bounds__(256) void k_agg(
    const ushort_t* __restrict__ X, const int* __restrict__ row_ptr,
    const int* __restrict__ srcs, ushort_t* __restrict__ out, int dummy)
{
    int w = threadIdx.x >> 6, lane = threadIdx.x & 63;
    int n = blockIdx.x * 4 + w;
    int col = blockIdx.y * 128 + lane * 2;
    int beg = row_ptr[n], end = row_ptr[n + 1];
    int deg = end - beg;
    float a0=0.f,a1=0.f, p0=0.f,p1=0.f, c0=0.f,c1=0.f, d0=0.f,d1=0.f;

    for (int base = beg; base < end; base += 64){
        int rem = end - base;
        int sr = (lane < rem) ? srcs[base + lane] : dummy;
        int cnt = rem < 64 ? rem : 64;
        #pragma unroll
        for (int k = 0; k < 4; ++k){
            if (k * 16 < cnt){
                int L = k * 16;
                AGG_EDGE(L + 0,  a) AGG_EDGE(L + 1,  p) AGG_EDGE(L + 2,  c) AGG_EDGE(L + 3,  d)
                AGG_EDGE(L + 4,  a) AGG_EDGE(L + 5,  p) AGG_EDGE(L + 6,  c) AGG_EDGE(L + 7,  d)
                AGG_EDGE(L + 8,  a) AGG_EDGE(L + 9,  p) AGG_EDGE(L + 10, c) AGG_EDGE(L + 11, d)
                AGG_EDGE(L + 12, a) AGG_EDGE(L + 13, p) AGG_EDGE(L + 14, c) AGG_EDGE(L + 15, d)
            }
        }
    }

    float r0 = (a0 + p0) + (c0 + d0);
    float r1 = (a1 + p1) + (c1 + d1);
    float inv = (deg > 0) ? 1.f / (float)deg : 1.f;
    uint_t o = (uint_t)f2b(r0 * inv) | ((uint_t)f2b(r1 * inv) << 16);
    *(uint_t*)&out[(size_t)n * 512 + col] = o;
}

// ---------------- final aggregation: fin = Q + mean_agg(P) ----------------

#define AGGF_EDGE(e, CH) { \
    int s_ = __builtin_amdgcn_readlane(sr, (e)); \
    uint_t v_ = *(const uint_t*)&P[((size_t)(uint_t)s_ << 8) + col]; \
    CH##0 += blo(v_); CH##1 += bhi(v_); }

__global__ __launch_bounds__(256) void k_aggf(
    const ushort_t* __restrict__ P, const int* __restrict__ row_ptr,
    const int* __restrict__ srcs, const float* __restrict__ Q,
    float* __restrict__ fin, float* __restrict__ mid2, int dummy)
{
    int w = threadIdx.x >> 6, lane = threadIdx.x & 63;
    int n = blockIdx.x * 4 + w;
    int col = blockIdx.y * 128 + lane * 2;
    int beg = row_ptr[n], end = row_ptr[n + 1];
    int deg = end - beg;
    float a0=0.f,a1=0.f, p0=0.f,p1=0.f, c0=0.f,c1=0.f, d0=0.f,d1=0.f;

    for (int base = beg; base < end; base += 64){
        int rem = end - base;
        int sr = (lane < rem) ? srcs[base + lane] : dummy;
        int cnt = rem < 64 ? rem : 64;
        #pragma unroll
        for (int k = 0; k < 4; ++k){
            if (k * 16 < cnt){
                int L = k * 16;
                AGGF_EDGE(L + 0,  a) AGGF_EDGE(L + 1,  p) AGGF_EDGE(L + 2,  c) AGGF_EDGE(L + 3,  d)
                AGGF_EDGE(L + 4,  a) AGGF_EDGE(L + 5,  p) AGGF_EDGE(L + 6,  c) AGGF_EDGE(L + 7,  d)
                AGGF_EDGE(L + 8,  a) AGGF_EDGE(L + 9,  p) AGGF_EDGE(L + 10, c) AGGF_EDGE(L + 11, d)
                AGGF_EDGE(L + 12, a) AGGF_EDGE(L + 13, p) AGGF_EDGE(L + 14, c) AGGF_EDGE(L + 15, d)
            }
        }
    }

    float r0 = (a0 + p0) + (c0 + d0);
    float r1 = (a1 + p1) + (c1 + d1);
    float inv = (deg > 0) ? 1.f / (float)deg : 1.f;
    float2 q = *(const float2*)&Q[(size_t)n * 256 + col];
    float2 o;
    o.x = q.x + r0 * inv;
    o.y = q.y + r1 * inv;
    *(float2*)&fin [(size_t)n * 256 + col] = o;
    *(float2*)&mid2[(size_t)n * 256 + col] = o;
}

// ---------------- fused SAGE layer (layers 0/1): one-batch BM=160, BN=64 --------
// T2 bank-swizzle (both-sides, measured neutral -> kept); 2-phase pipeline.
// Y(f32) = leaky(X@Ws^T + Agg@Wn^T + b) + X@Wr^T + rb ; bf16 shadow to YB

template<int DO, int BN, bool ACT, bool WRITE_BF>
__global__ __launch_bounds__(256, 2) void k_layer(
    const ushort_t* __restrict__ X, const ushort_t* __restrict__ G,
    const ushort_t* __restrict__ Ws, const ushort_t* __restrict__ Wn,
    const ushort_t* __restrict__ Wr,
    const float* __restrict__ b, const float* __restrict__ rb,
    float* __restrict__ Y, ushort_t* __restrict__ YB)
{
    constexpr int BM   = 160;
    constexpr int NT   = DO / BN;
    constexpr int WTN  = BN / 32;
    constexpr int NCH  = (2 * BM + 3 * BN) / 16;
    constexpr int CHPW = (NCH + 3) / 4;
    constexpr int OG   = BM * 32;
    constexpr int OS   = 2 * BM * 32;
    constexpr int WS32 = BN * 32;
    constexpr int BUFSZ = OS + 3 * WS32;
    __shared__ __align__(16) ushort_t smem[2][BUFSZ];

    int t = threadIdx.x;
    int bid = blockIdx.x;
    int r8 = bid & 7, q8 = bid >> 3;
    int m_t = (q8 / NT) * 8 + r8;
    int n_t = q8 % NT;
    if (m_t * BM >= N_NODES) return;
    int m0 = m_t * BM, n0 = n_t * BN;

    int lane = t & 63, w = t >> 6;
    int wr = w >> 1, wc = w & 1;

    const ushort_t* gptr[CHPW];
    int coff[CHPW];
    bool gv[CHPW];
    int rl = lane >> 2;
    int sl = ((lane & 3) ^ ((rl >> 1) & 3)) * 8;
    #pragma unroll
    for (int i = 0; i < CHPW; ++i){
        int qq = w * CHPW + i;
        gv[i] = (qq < NCH);
        int qc = gv[i] ? qq : 0;
        const ushort_t* gA; int rowbase, off;
        if (qc < 10)      { gA = X;  rowbase = m0 + qc * 16;        off = qc * 512; }
        else if (qc < 20) { gA = G;  rowbase = m0 + (qc - 10) * 16; off = OG + (qc - 10) * 512; }
        else {
            int q2 = qc - 20;
            int sec = q2 / (BN / 16), wi = q2 % (BN / 16);
            gA = (sec == 0) ? Ws : (sec == 1) ? Wn : Wr;
            rowbase = n0 + wi * 16;
            off = OS + sec * WS32 + wi * 512;
        }
        gptr[i] = gA + (size_t)(rowbase + rl) * 512 + sl;
        coff[i] = off;
    }

    f32x4 accS[5][WTN] = {}, accG[5][WTN] = {}, accR[5][WTN] = {};
    int r16 = lane & 15;
    int arow = wr * 80 + r16;
    int brow = wc * (BN / 2) + r16;
    int kk = ((lane >> 4) ^ ((r16 >> 1) & 3)) * 8;

    #pragma unroll
    for (int i = 0; i < CHPW; ++i) if (gv[i]) gll16(gptr[i], &smem[0][coff[i]]);
    __syncthreads();

    int cur = 0;
    for (int ks = 0; ks < 16; ++ks){
        if (ks < 15){
            int k0 = (ks + 1) * 32;
            #pragma unroll
            for (int i = 0; i < CHPW; ++i) if (gv[i]) gll16(gptr[i] + k0, &smem[cur ^ 1][coff[i]]);
        }

        const ushort_t* sb = smem[cur];
        bf16x8 ax[5], ag[5], bs[WTN], bn_[WTN], brr[WTN];
        #pragma unroll
        for (int m = 0; m < 5; ++m){
            ax[m] = *(const bf16x8*)&sb[(arow + m * 16) * 32 + kk];
            ag[m] = *(const bf16x8*)&sb[OG + (arow + m * 16) * 32 + kk];
        }
        #pragma unroll
        for (int n = 0; n < WTN; ++n){
            bs[n]  = *(const bf16x8*)&sb[OS            + (brow + n * 16) * 32 + kk];
            bn_[n] = *(const bf16x8*)&sb[OS + WS32     + (brow + n * 16) * 32 + kk];
            brr[n] = *(const bf16x8*)&sb[OS + 2 * WS32 + (brow + n * 16) * 32 + kk];
        }
        #pragma unroll
        for (int m = 0; m < 5; ++m)
            #pragma unroll
            for (int n = 0; n < WTN; ++n){
                accS[m][n] = __builtin_amdgcn_mfma_f32_16x16x32_bf16(ax[m], bs[n],  accS[m][n], 0, 0, 0);
                accG[m][n] = __builtin_amdgcn_mfma_f32_16x16x32_bf16(ag[m], bn_[n], accG[m][n], 0, 0, 0);
                accR[m][n] = __builtin_amdgcn_mfma_f32_16x16x32_bf16(ax[m], brr[n], accR[m][n], 0, 0, 0);
            }

        __syncthreads();
        cur ^= 1;
    }

    int col_l = lane & 15;
    int row_l = (lane >> 4) * 4;
    #pragma unroll
    for (int n = 0; n < WTN; ++n){
        int col = n0 + wc * (BN / 2) + n * 16 + col_l;
        float bb = b[col], rbb = rb[col];
        #pragma unroll
        for (int m = 0; m < 5; ++m){
            #pragma unroll
            for (int j = 0; j < 4; ++j){
                int row = m0 + wr * 80 + m * 16 + row_l + j;
                if (row < N_NODES){
                    float v = accS[m][n][j] + accG[m][n][j] + bb;
                    if (ACT) v = (v > 0.f) ? v : 0.01f * v;
                    v += accR[m][n][j] + rbb;
                    Y[(size_t)row * DO + col] = v;
                    if (WRITE_BF) YB[(size_t)row * DO + col] = f2b(v);
                }
            }
        }
    }
}

// ---------------- layer 2 GEMM: P = X@Wn2^T (bf16), Q = X@Wsr2^T + (b2+rb2) (f32) --

__global__ __launch_bounds__(256, 2) void k_layer2(
    const ushort_t* __restrict__ X,
    const ushort_t* __restrict__ Wn, const ushort_t* __restrict__ Wsr,
    const float* __restrict__ b, const float* __restrict__ rb,
    ushort_t* __restrict__ Pout, float* __restrict__ Qout)
{
    constexpr int BM = 160, BN = 32, NT = DOUT / BN;
    constexpr int NCH = 10 + 2 * (BN / 16);
    constexpr int CHPW = 4;
    constexpr int OWN = BM * 32;
    constexpr int OWS = OWN + BN * 32;
    constexpr int BUFSZ = OWS + BN * 32;
    __shared__ __align__(16) ushort_t smem[2][BUFSZ];

    int t = threadIdx.x;
    int bid = blockIdx.x;
    int r8 = bid & 7, q8 = bid >> 3;
    int m_t = (q8 / NT) * 8 + r8;
    int n_t = q8 % NT;
    if (m_t * BM >= N_NODES) return;
    int m0 = m_t * BM, n0 = n_t * BN;

    int lane = t & 63, w = t >> 6;
    int wr = w >> 1, wc = w & 1;

    const ushort_t* gptr[CHPW];
    int coff[CHPW];
    bool gv[CHPW];
    int rl = lane >> 2;
    int sl = ((lane & 3) ^ ((rl >> 1) & 3)) * 8;
    #pragma unroll
    for (int i = 0; i < CHPW; ++i){
        int qq = w * CHPW + i;
        gv[i] = (qq < NCH);
        int qc = gv[i] ? qq : 0;
        const ushort_t* gA; int rowbase, off;
        if (qc < 10)      { gA = X;   rowbase = m0 + qc * 16;        off = qc * 512; }
        else if (qc < 12) { gA = Wn;  rowbase = n0 + (qc - 10) * 16; off = OWN + (qc - 10) * 512; }
        else              { gA = Wsr; rowbase = n0 + (qc - 12) * 16; off = OWS + (qc - 12) * 512; }
        gptr[i] = gA + (size_t)(rowbase + rl) * 512 + sl;
        coff[i] = off;
    }

    f32x4 accP[5] = {}, accQ[5] = {};
    int r16 = lane & 15;
    int arow = wr * 80 + r16;
    int brow = wc * 16 + r16;
    int kk = ((lane >> 4) ^ ((r16 >> 1) & 3)) * 8;

    #pragma unroll
    for (int i = 0; i < CHPW; ++i) if (gv[i]) gll16(gptr[i], &smem[0][coff[i]]);
    __syncthreads();

    int cur = 0;
    for (int ks = 0; ks < 16; ++ks){
        if (ks < 15){
            int k0 = (ks + 1) * 32;
            #pragma unroll
            for (int i = 0; i < CHPW; ++i) if (gv[i]) gll16(gptr[i] + k0, &smem[cur ^ 1][coff[i]]);
        }

        const ushort_t* sb = smem[cur];
        bf16x8 ax[5];
        #pragma unroll
        for (int m = 0; m < 5; ++m)
            ax[m] = *(const bf16x8*)&sb[(arow + m * 16) * 32 + kk];
        bf16x8 bn_ = *(const bf16x8*)&sb[OWN + brow * 32 + kk];
        bf16x8 bsr = *(const bf16x8*)&sb[OWS + brow * 32 + kk];
        #pragma unroll
        for (int m = 0; m < 5; ++m){
            accP[m] = __builtin_amdgcn_mfma_f32_16x16x32_bf16(ax[m], bn_, accP[m], 0, 0, 0);
            accQ[m] = __builtin_amdgcn_mfma_f32_16x16x32_bf16(ax[m], bsr, accQ[m], 0, 0, 0);
        }

        __syncthreads();
        cur ^= 1;
    }

    int col_l = lane & 15;
    int row_l = (lane >> 4) * 4;
    int col = n0 + wc * 16 + col_l;
    float bb = b[col] + rb[col];
    #pragma unroll
    for (int m = 0; m < 5; ++m){
        #pragma unroll
        for (int j = 0; j < 4; ++j){
            int row = m0 + wr * 80 + m * 16 + row_l + j;
            if (row < N_NODES){
                Qout[(size_t)row * DOUT + col] = accQ[m][j] + bb;
                Pout[(size_t)row * DOUT + col] = f2b(accP[m][j]);
            }
        }
    }
}

// ---------------- launch ----------------

extern "C" void kernel_launch(void* const* d_in, const int* in_sizes, int n_in,
                              void* d_out, int out_size, void* d_ws, size_t ws_size,
                              hipStream_t stream) {
    const int* edge  = (const int*)d_in[0];
    const int* e_src = edge;
    const int* e_dst = edge + N_EDGES;
    const float* w_pe = (const float*)d_in[1];
    const float* b_pe = (const float*)d_in[2];
    const float* ws0 = (const float*)d_in[3];
    const float* wn0 = (const float*)d_in[4];
    const float* b0  = (const float*)d_in[5];
    const float* wr0 = (const float*)d_in[6];
    const float* rb0 = (const float*)d_in[7];
    const float* ws1 = (const float*)d_in[8];
    const float* wn1 = (const float*)d_in[9];
    const float* b1  = (const float*)d_in[10];
    const float* wr1 = (const float*)d_in[11];
    const float* rb1 = (const float*)d_in[12];
    const float* ws2 = (const float*)d_in[13];
    const float* wn2 = (const float*)d_in[14];
    const float* b2  = (const float*)d_in[15];
    const float* wr2 = (const float*)d_in[16];
    const float* rb2 = (const float*)d_in[17];

    char* wsb = (char*)d_ws;
    ushort_t* h0   = (ushort_t*)wsb;                       // 10,240,000 B @ 0
    ushort_t* hb   = (ushort_t*)(wsb + 10240000);          // 10,240,000 B
    ushort_t* aggb = (ushort_t*)(wsb + 20480000);          // 10,240,000 B (pb aliases)
    ushort_t* wbf  = (ushort_t*)(wsb + 30720000);          // 3,932,160 B
    int* deg     = (int*)(wsb + 34652160);                 // 10016 ints
    int* row_ptr = deg + 10016;
    int* cursor  = row_ptr + 10016;
    int* srcs    = cursor + 10016;                         // 320000 ints -> ends 36,052,352
    uint_t* zp   = (uint_t*)(wsb + 36052992);              // 1KB zero row (1024-aligned)
    const int dummy_h0 = 35208;   // (36052992 - 0) / 1024          (1KB rows)
    const int dummy_hb = 25208;   // (36052992 - 10240000) / 1024   (1KB rows)
    const int dummy_pb = 30416;   // (36052992 - 20480000) / 512    (512B rows)

    ushort_t* wbf0s = wbf;
    ushort_t* wbf0n = wbf + 262144;
    ushort_t* wbf0r = wbf + 524288;
    ushort_t* wbf1s = wbf + 786432;
    ushort_t* wbf1n = wbf + 1048576;
    ushort_t* wbf1r = wbf + 1310720;
    ushort_t* wbf2n = wbf + 1572864;   // Wn2
    ushort_t* wbf2sr= wbf + 1703936;   // Ws2 + Wr2

    float* out  = (float*)d_out;
    float* fin  = out;               // [10000][256]
    float* mid0 = out + 2560000;     // [10000][512]
    float* mid1 = out + 7680000;     // [10000][512]
    float* mid2 = out + 12800000;    // [10000][256]
    ushort_t* pb = aggb;             // P = X@Wn2^T, bf16 [10000][256]

    CvtArgs ca;
    ca.s[0]=ws0; ca.s[1]=wn0; ca.s[2]=wr0;
    ca.s[3]=ws1; ca.s[4]=wn1; ca.s[5]=wr1;
    ca.s[6]=wn2; ca.s[7]=ws2;
    for (int i = 0; i < 8; ++i) ca.s2[i] = nullptr;
    ca.s2[7] = wr2;                                  // Wsr2 = Ws2 + Wr2
    ca.d[0]=wbf0s; ca.d[1]=wbf0n; ca.d[2]=wbf0r;
    ca.d[3]=wbf1s; ca.d[4]=wbf1n; ca.d[5]=wbf1r;
    ca.d[6]=wbf2n; ca.d[7]=wbf2sr;
    for (int i = 0; i < 6; ++i) ca.n[i] = 262144;
    ca.n[6] = 131072; ca.n[7] = 131072;

    // fused prologue: pe (1256) + cvt (1024) + zero (40)
    k_pro<<<2320, 256, 0, stream>>>(w_pe, b_pe, h0, ca, deg, zp);

    k_degree <<<1250, 256, 0, stream>>>(e_dst, deg);
    k_scan   <<<1, 256, 0, stream>>>(deg, row_ptr, cursor);
    k_scatter<<<1250, 256, 0, stream>>>(e_src, e_dst, cursor, srcs);

    k_agg<<<dim3(2500, 4), 256, 0, stream>>>(h0, row_ptr, srcs, aggb, dummy_h0);
    k_layer<512, 64, true, true ><<<dim3(512), 256, 0, stream>>>(
        h0, aggb, wbf0s, wbf0n, wbf0r, b0, rb0, mid0, hb);

    k_agg<<<dim3(2500, 4), 256, 0, stream>>>(hb, row_ptr, srcs, aggb, dummy_hb);
    k_layer<512, 64, true, true ><<<dim3(512), 256, 0, stream>>>(
        hb, aggb, wbf1s, wbf1n, wbf1r, b1, rb1, mid1, h0);

    // layer 2 via agg-commute: P = X@Wn2^T, Q = X@(Ws2+Wr2)^T + (b2+rb2);
    // fin = mid2 = Q + mean_agg(P)
    k_layer2<<<dim3(512), 256, 0, stream>>>(h0, wbf2n, wbf2sr, b2, rb2, pb, mid2);
    k_aggf<<<dim3(2500, 2), 256, 0, stream>>>(pb, row_ptr, srcs, mid2, fin, mid2, dummy_pb);
}